// Round 3
// baseline (1071.958 us; speedup 1.0000x reference)
//
#include <hip/hip_runtime.h>
#include <stdint.h>

#define B_   8
#define T_   2048
#define C_   1024
#define H_   2048
#define E_   8
#define CAP_ 640
#define RPE_ (B_*CAP_)   // 5120 rows per expert (max)
#define BT_  (B_*T_)     // 16384 tokens
#define NE_  2           // experts per chunk

typedef __attribute__((ext_vector_type(8))) short bf16x8;
typedef __attribute__((ext_vector_type(4))) float f32x4;

static __device__ __forceinline__ unsigned short f2bf(float f){
  union { float f; uint32_t u; } a; a.f = f;
  uint32_t u = a.u;
  uint32_t r = (u + 0x7FFFu + ((u >> 16) & 1u)) >> 16;   // RTNE
  return (unsigned short)r;
}

#define GLD16(gp, lp) __builtin_amdgcn_global_load_lds( \
    (__attribute__((address_space(1))) void*)(gp), \
    (__attribute__((address_space(3))) void*)(lp), 16, 0, 0)

// ---------------- router: logits (fp64 acc), softmax, top-2, x->bf16 ----------------
__global__ __launch_bounds__(256) void router_kernel(
    const float* __restrict__ x, const float* __restrict__ wr,
    unsigned short* __restrict__ xbf, float* __restrict__ probs2, int* __restrict__ idx2)
{
  int bt = blockIdx.x;
  int tid = threadIdx.x;
  const float4 v = ((const float4*)(x + (size_t)bt*C_))[tid];
  ushort4 u;
  u.x = f2bf(v.x); u.y = f2bf(v.y); u.z = f2bf(v.z); u.w = f2bf(v.w);
  ((ushort4*)(xbf + (size_t)bt*C_))[tid] = u;

  double p[8];
  #pragma unroll
  for (int e=0;e<8;e++) p[e]=0.0;
  const float xv[4] = {v.x, v.y, v.z, v.w};
  #pragma unroll
  for (int j=0;j<4;j++){
    int c = tid*4+j;
    const float* wrow = wr + c*8;
    #pragma unroll
    for (int e=0;e<8;e++) p[e] += (double)xv[j] * (double)wrow[e];
  }
  __shared__ double red[8][256];
  #pragma unroll
  for (int e=0;e<8;e++) red[e][tid] = p[e];
  __syncthreads();
  for (int s=128; s>0; s>>=1){
    if (tid < s){
      #pragma unroll
      for (int e=0;e<8;e++) red[e][tid] += red[e][tid+s];
    }
    __syncthreads();
  }
  if (tid==0){
    double lg[8];
    #pragma unroll
    for (int e=0;e<8;e++) lg[e]=red[e][0];
    double mx = lg[0];
    #pragma unroll
    for (int e=1;e<8;e++) if (lg[e]>mx) mx=lg[e];
    double s=0.0, ex[8];
    #pragma unroll
    for (int e=0;e<8;e++){ ex[e]=exp(lg[e]-mx); s+=ex[e]; }
    int i1=0; double b1=ex[0];
    #pragma unroll
    for (int e=1;e<8;e++) if (ex[e]>b1){ b1=ex[e]; i1=e; }
    int i2=-1; double b2=-1.0;
    #pragma unroll
    for (int e=0;e<8;e++) if (e!=i1 && ex[e]>b2){ b2=ex[e]; i2=e; }
    probs2[bt*2+0] = (float)(b1/s);
    probs2[bt*2+1] = (float)(b2/s);
    idx2[bt*2+0] = i1;
    idx2[bt*2+1] = i2;
  }
}

// ---------------- weight transpose fp32[NE][K][N] -> bf16[NE][N][K] ----------------
__global__ __launch_bounds__(256) void transp_kernel(
    const float* __restrict__ src, unsigned short* __restrict__ dst, int K, int N)
{
  __shared__ float t[32][33];
  int e = blockIdx.z;   // chunk-local
  int n0 = blockIdx.x*32, k0 = blockIdx.y*32;
  int tx = threadIdx.x & 31, ty = threadIdx.x >> 5;
  const float* s = src + ((size_t)e*K + k0)*N + n0;
  #pragma unroll
  for (int i=0;i<32;i+=8) t[ty+i][tx] = s[(size_t)(ty+i)*N + tx];
  __syncthreads();
  unsigned short* d = dst + ((size_t)e*N + n0)*K + k0;
  #pragma unroll
  for (int i=0;i<32;i+=8) d[(size_t)(ty+i)*K + tx] = f2bf(t[tx][ty+i]);
}

// ---------------- dispatch scan: exact k-major cumsum slot assignment ----------------
__global__ void scan_kernel(const int* __restrict__ idx2, int* __restrict__ pos, int* __restrict__ cnt)
{
  int b = blockIdx.x, lane = threadIdx.x;  // 64 threads
  unsigned long long below = (lane == 0) ? 0ull : (~0ull >> (64 - lane));
  int base = 0;  // lanes 0..7 hold per-expert running counts
  for (int k=0;k<2;k++){
    for (int c0=0;c0<T_;c0+=64){
      int t = c0 + lane;
      int e = idx2[((b*T_ + t)<<1) + k];
      unsigned long long mym = 0; int addv = 0;
      #pragma unroll
      for (int ee=0; ee<8; ++ee){
        unsigned long long m = __ballot(e == ee);
        if (ee == e) mym = m;
        if (lane == ee) addv = __popcll(m);
      }
      int mybase = __shfl(base, e, 64);
      pos[((b*T_+t)<<1)+k] = mybase + __popcll(mym & below);
      base += addv;
    }
  }
  if (lane < 8) cnt[b*8 + lane] = (base < CAP_) ? base : CAP_;
}

__global__ void offsets_kernel(const int* __restrict__ cnt, int* __restrict__ off, int* __restrict__ Me)
{
  int e = threadIdx.x;
  if (e < 8){
    int s = 0;
    for (int b=0;b<8;b++){ off[e*8+b] = s; s += cnt[b*8+e]; }
    Me[e] = s;
  }
}

// fill: per-row token index and combine weight (compact per-expert rows)
__global__ void fill_kernel(const int* __restrict__ idx2, const int* __restrict__ pos,
                            const int* __restrict__ off, const float* __restrict__ probs2,
                            int* __restrict__ token_src, float* __restrict__ row_prob)
{
  int a = blockIdx.x*256 + threadIdx.x;
  if (a >= BT_*2) return;
  int bt = a >> 1, k = a & 1;
  int b = bt >> 11;
  int e = idx2[bt*2+k];
  int p = pos[bt*2+k];
  if (p < CAP_){
    int r = e*RPE_ + off[e*8+b] + p;
    token_src[r] = bt;
    row_prob[r] = probs2[bt*2+k];
  }
}

// ---------------- GEMM1: act = silu(Xg @ WgT^T) * (Xg @ WfcT^T) ----------------
__global__ __launch_bounds__(256) void gemm1_kernel(
    const unsigned short* __restrict__ xbf,
    const unsigned short* __restrict__ wfcT,   // chunk-local [NE][H][C]
    const unsigned short* __restrict__ wgT,
    const int* __restrict__ token_src,         // global [E][RPE]
    const int* __restrict__ Me,
    unsigned short* __restrict__ act,          // chunk-local [NE][RPE][H]
    int e0)
{
  const int ez = blockIdx.z, e = e0 + ez, mt = blockIdx.y, nt = blockIdx.x;
  const int M = Me[e];
  if (mt*128 >= M) return;

  __shared__ __align__(16) unsigned char ldsA[16384];
  __shared__ __align__(16) unsigned char ldsBf[16384];
  __shared__ __align__(16) unsigned char ldsBg[16384];

  const int tid = threadIdx.x;
  const int w = tid >> 6, l = tid & 63;
  const int wrow = w >> 1, wcol = w & 1;
  const int r8 = l >> 3;
  const unsigned swz16 = (unsigned)(((l & 7) ^ r8) * 16);

  unsigned offA[4], offBf[4], ldsOff[4];
  #pragma unroll
  for (int j = 0; j < 4; ++j){
    int row = w*32 + j*8 + r8;
    int tok = token_src[e*RPE_ + mt*128 + row];
    offA[j]  = (unsigned)tok * 2048u + swz16;
    int nr   = nt*128 + row;
    offBf[j] = (unsigned)(ez*H_ + nr) * 2048u + swz16;
    ldsOff[j] = (unsigned)(w*32 + j*8) * 128u;
  }

  f32x4 acch[4][4], accg[4][4];
  #pragma unroll
  for (int i=0;i<4;i++)
    #pragma unroll
    for (int j=0;j<4;j++){ acch[i][j] = (f32x4){0.f,0.f,0.f,0.f}; accg[i][j] = (f32x4){0.f,0.f,0.f,0.f}; }

  const unsigned char* gA  = (const unsigned char*)xbf;
  const unsigned char* gBf = (const unsigned char*)wfcT;
  const unsigned char* gBg = (const unsigned char*)wgT;

  for (int k0 = 0; k0 < 1024; k0 += 64){
    __syncthreads();
    const unsigned kb = (unsigned)k0 * 2u;
    #pragma unroll
    for (int j=0;j<4;++j) GLD16(gA  + offA[j]  + kb, ldsA  + ldsOff[j]);
    #pragma unroll
    for (int j=0;j<4;++j) GLD16(gBf + offBf[j] + kb, ldsBf + ldsOff[j]);
    #pragma unroll
    for (int j=0;j<4;++j) GLD16(gBg + offBf[j] + kb, ldsBg + ldsOff[j]);
    __syncthreads();

    #pragma unroll
    for (int kh=0; kh<2; ++kh){
      bf16x8 afr[4];
      #pragma unroll
      for (int fm=0; fm<4; ++fm){
        int row = wrow*64 + fm*16 + (l & 15);
        int gnum = kh*4 + (l >> 4);
        int byt = row*128 + ((gnum ^ (row & 7)) * 16);
        afr[fm] = *(const bf16x8*)(ldsA + byt);
      }
      bf16x8 bfr[4];
      #pragma unroll
      for (int fn=0; fn<4; ++fn){
        int row = wcol*64 + fn*16 + (l & 15);
        int gnum = kh*4 + (l >> 4);
        int byt = row*128 + ((gnum ^ (row & 7)) * 16);
        bfr[fn] = *(const bf16x8*)(ldsBf + byt);
      }
      #pragma unroll
      for (int fm=0; fm<4; ++fm)
        #pragma unroll
        for (int fn=0; fn<4; ++fn)
          acch[fm][fn] = __builtin_amdgcn_mfma_f32_16x16x32_bf16(afr[fm], bfr[fn], acch[fm][fn], 0,0,0);
      #pragma unroll
      for (int fn=0; fn<4; ++fn){
        int row = wcol*64 + fn*16 + (l & 15);
        int gnum = kh*4 + (l >> 4);
        int byt = row*128 + ((gnum ^ (row & 7)) * 16);
        bfr[fn] = *(const bf16x8*)(ldsBg + byt);
      }
      #pragma unroll
      for (int fm=0; fm<4; ++fm)
        #pragma unroll
        for (int fn=0; fn<4; ++fn)
          accg[fm][fn] = __builtin_amdgcn_mfma_f32_16x16x32_bf16(afr[fm], bfr[fn], accg[fm][fn], 0,0,0);
    }
  }

  #pragma unroll
  for (int fm=0; fm<4; ++fm){
    #pragma unroll
    for (int fn=0; fn<4; ++fn){
      #pragma unroll
      for (int r=0; r<4; ++r){
        int row = mt*128 + wrow*64 + fm*16 + (l>>4)*4 + r;
        int col = nt*128 + wcol*64 + fn*16 + (l & 15);
        float h = acch[fm][fn][r];
        float g = accg[fm][fn][r];
        float a = (g / (1.f + __expf(-g))) * h;
        act[((size_t)ez*RPE_ + row)*(size_t)H_ + col] = f2bf(a);
      }
    }
  }
}

// ---------------- GEMM2: o = act @ WprojT^T, scatter p*o into y (atomic) ----------------
__global__ __launch_bounds__(256) void gemm2_kernel(
    const unsigned short* __restrict__ act,     // chunk-local [NE][RPE][H]
    const unsigned short* __restrict__ wprojT,  // chunk-local [NE][C][H]
    const int* __restrict__ token_src,          // global [E][RPE]
    const float* __restrict__ row_prob,
    const int* __restrict__ Me,
    float* __restrict__ y,
    int e0)
{
  const int ez = blockIdx.z, e = e0 + ez, mt = blockIdx.y, nt = blockIdx.x;  // nt 0..7
  const int M = Me[e];
  if (mt*128 >= M) return;

  __shared__ __align__(16) unsigned char ldsA[16384];
  __shared__ __align__(16) unsigned char ldsB[16384];

  const int tid = threadIdx.x;
  const int w = tid >> 6, l = tid & 63;
  const int wrow = w >> 1, wcol = w & 1;
  const int r8 = l >> 3;
  const unsigned swz16 = (unsigned)(((l & 7) ^ r8) * 16);

  unsigned offA[4], offB[4], ldsOff[4];
  #pragma unroll
  for (int j = 0; j < 4; ++j){
    int row = w*32 + j*8 + r8;
    offA[j] = (unsigned)(ez*RPE_ + mt*128 + row) * 4096u + swz16;
    offB[j] = (unsigned)(ez*C_ + nt*128 + row) * 4096u + swz16;
    ldsOff[j] = (unsigned)(w*32 + j*8) * 128u;
  }

  f32x4 acc[4][4];
  #pragma unroll
  for (int i=0;i<4;i++)
    #pragma unroll
    for (int j=0;j<4;j++) acc[i][j] = (f32x4){0.f,0.f,0.f,0.f};

  const unsigned char* gA = (const unsigned char*)act;
  const unsigned char* gB = (const unsigned char*)wprojT;

  for (int k0 = 0; k0 < 2048; k0 += 64){
    __syncthreads();
    const unsigned kb = (unsigned)k0 * 2u;
    #pragma unroll
    for (int j=0;j<4;++j) GLD16(gA + offA[j] + kb, ldsA + ldsOff[j]);
    #pragma unroll
    for (int j=0;j<4;++j) GLD16(gB + offB[j] + kb, ldsB + ldsOff[j]);
    __syncthreads();

    #pragma unroll
    for (int kh=0; kh<2; ++kh){
      bf16x8 afr[4], bfr[4];
      #pragma unroll
      for (int fm=0; fm<4; ++fm){
        int row = wrow*64 + fm*16 + (l & 15);
        int gnum = kh*4 + (l >> 4);
        int byt = row*128 + ((gnum ^ (row & 7)) * 16);
        afr[fm] = *(const bf16x8*)(ldsA + byt);
      }
      #pragma unroll
      for (int fn=0; fn<4; ++fn){
        int row = wcol*64 + fn*16 + (l & 15);
        int gnum = kh*4 + (l >> 4);
        int byt = row*128 + ((gnum ^ (row & 7)) * 16);
        bfr[fn] = *(const bf16x8*)(ldsB + byt);
      }
      #pragma unroll
      for (int fm=0; fm<4; ++fm)
        #pragma unroll
        for (int fn=0; fn<4; ++fn)
          acc[fm][fn] = __builtin_amdgcn_mfma_f32_16x16x32_bf16(afr[fm], bfr[fn], acc[fm][fn], 0,0,0);
    }
  }

  // epilogue: scatter p * o[row][col] into y[token][col]
  #pragma unroll
  for (int fm=0; fm<4; ++fm){
    #pragma unroll
    for (int r=0; r<4; ++r){
      int rloc = mt*128 + wrow*64 + fm*16 + (l>>4)*4 + r;
      if (rloc < M){
        int bt  = token_src[e*RPE_ + rloc];
        float p = row_prob[e*RPE_ + rloc];
        float* yrow = y + (size_t)bt*C_;
        #pragma unroll
        for (int fn=0; fn<4; ++fn){
          int col = nt*128 + wcol*64 + fn*16 + (l & 15);
          atomicAdd(yrow + col, p * acc[fm][fn][r]);
        }
      }
    }
  }
}

extern "C" void kernel_launch(void* const* d_in, const int* in_sizes, int n_in,
                              void* d_out, int out_size, void* d_ws, size_t ws_size,
                              hipStream_t stream)
{
  const float* x   = (const float*)d_in[0];
  const float* wr  = (const float*)d_in[1];
  const float* wfc = (const float*)d_in[2];
  const float* wg  = (const float*)d_in[3];
  const float* wpj = (const float*)d_in[4];
  float* y = (float*)d_out;

  unsigned char* ws = (unsigned char*)d_ws;
  const size_t szXBF = (size_t)BT_*C_*2;          // 33,554,432
  const size_t szWC  = (size_t)NE_*C_*H_*2;       //  8,388,608 per weight chunk
  const size_t szACT = (size_t)NE_*RPE_*H_*2;     // 41,943,040

  size_t oXBF = 0;
  size_t oWFT = oXBF + szXBF;
  size_t oWGT = oWFT + szWC;
  size_t oWPT = oWGT + szWC;
  size_t oACT = oWPT + szWC;
  size_t oSM  = oACT + szACT;                     // 100,663,296

  float* probs2    = (float*)(ws + oSM);
  int*   idx2      = (int*)(ws + oSM + 1*131072);
  int*   pos       = (int*)(ws + oSM + 2*131072);
  int*   token_src = (int*)(ws + oSM + 3*131072);
  float* row_prob  = (float*)(ws + oSM + 3*131072 + (size_t)E_*RPE_*4);
  int*   cnt       = (int*)(ws + oSM + 3*131072 + 2*(size_t)E_*RPE_*4);
  int*   off       = cnt + 64;
  int*   Me        = off + 64;

  size_t need = oSM + 3*131072 + 2*(size_t)E_*RPE_*4 + 1024;   // ~101.4 MB
  if (ws_size < need) return;

  unsigned short* xbf     = (unsigned short*)(ws + oXBF);
  unsigned short* wfcTc   = (unsigned short*)(ws + oWFT);
  unsigned short* wgTc    = (unsigned short*)(ws + oWGT);
  unsigned short* wprojTc = (unsigned short*)(ws + oWPT);
  unsigned short* actc    = (unsigned short*)(ws + oACT);

  hipMemsetAsync(y, 0, (size_t)out_size*4, stream);
  hipMemsetAsync(token_src, 0, (size_t)E_*RPE_*4, stream);

  router_kernel<<<BT_, 256, 0, stream>>>(x, wr, xbf, probs2, idx2);
  scan_kernel<<<B_, 64, 0, stream>>>(idx2, pos, cnt);
  offsets_kernel<<<1, 64, 0, stream>>>(cnt, off, Me);
  fill_kernel<<<(BT_*2+255)/256, 256, 0, stream>>>(idx2, pos, off, probs2, token_src, row_prob);

  for (int e0 = 0; e0 < E_; e0 += NE_){
    const float* wfc_c = wfc + (size_t)e0*C_*H_;
    const float* wg_c  = wg  + (size_t)e0*C_*H_;
    const float* wpj_c = wpj + (size_t)e0*H_*C_;
    transp_kernel<<<dim3(H_/32, C_/32, NE_), 256, 0, stream>>>(wfc_c, wfcTc, C_, H_);
    transp_kernel<<<dim3(H_/32, C_/32, NE_), 256, 0, stream>>>(wg_c,  wgTc,  C_, H_);
    transp_kernel<<<dim3(C_/32, H_/32, NE_), 256, 0, stream>>>(wpj_c, wprojTc, H_, C_);
    gemm1_kernel<<<dim3(H_/128, RPE_/128, NE_), 256, 0, stream>>>(xbf, wfcTc, wgTc, token_src, Me, actc, e0);
    gemm2_kernel<<<dim3(C_/128, RPE_/128, NE_), 256, 0, stream>>>(actc, wprojTc, token_src, row_prob, Me, y, e0);
  }
}

// Round 4
// 837.148 us; speedup vs baseline: 1.2805x; 1.2805x over previous
//
#include <hip/hip_runtime.h>
#include <stdint.h>

#define B_   8
#define T_   2048
#define C_   1024
#define H_   2048
#define E_   8
#define CAP_ 640
#define RPE_ (B_*CAP_)   // 5120 rows per expert (max)
#define BT_  (B_*T_)     // 16384 tokens
#define NE_  2           // experts per chunk

typedef __attribute__((ext_vector_type(8))) short bf16x8;
typedef __attribute__((ext_vector_type(4))) float f32x4;

static __device__ __forceinline__ unsigned short f2bf(float f){
  union { float f; uint32_t u; } a; a.f = f;
  uint32_t u = a.u;
  uint32_t r = (u + 0x7FFFu + ((u >> 16) & 1u)) >> 16;   // RTNE
  return (unsigned short)r;
}

#define GLD16(gp, lp) __builtin_amdgcn_global_load_lds( \
    (__attribute__((address_space(1))) void*)(gp), \
    (__attribute__((address_space(3))) void*)(lp), 16, 0, 0)

// ---------------- router: logits (fp64 acc), softmax, top-2, x->bf16 ----------------
__global__ __launch_bounds__(256) void router_kernel(
    const float* __restrict__ x, const float* __restrict__ wr,
    unsigned short* __restrict__ xbf, float* __restrict__ probs2, int* __restrict__ idx2)
{
  int bt = blockIdx.x;
  int tid = threadIdx.x;
  const float4 v = ((const float4*)(x + (size_t)bt*C_))[tid];
  ushort4 u;
  u.x = f2bf(v.x); u.y = f2bf(v.y); u.z = f2bf(v.z); u.w = f2bf(v.w);
  ((ushort4*)(xbf + (size_t)bt*C_))[tid] = u;

  double p[8];
  #pragma unroll
  for (int e=0;e<8;e++) p[e]=0.0;
  const float xv[4] = {v.x, v.y, v.z, v.w};
  #pragma unroll
  for (int j=0;j<4;j++){
    int c = tid*4+j;
    const float* wrow = wr + c*8;
    #pragma unroll
    for (int e=0;e<8;e++) p[e] += (double)xv[j] * (double)wrow[e];
  }
  __shared__ double red[8][256];
  #pragma unroll
  for (int e=0;e<8;e++) red[e][tid] = p[e];
  __syncthreads();
  for (int s=128; s>0; s>>=1){
    if (tid < s){
      #pragma unroll
      for (int e=0;e<8;e++) red[e][tid] += red[e][tid+s];
    }
    __syncthreads();
  }
  if (tid==0){
    double lg[8];
    #pragma unroll
    for (int e=0;e<8;e++) lg[e]=red[e][0];
    double mx = lg[0];
    #pragma unroll
    for (int e=1;e<8;e++) if (lg[e]>mx) mx=lg[e];
    double s=0.0, ex[8];
    #pragma unroll
    for (int e=0;e<8;e++){ ex[e]=exp(lg[e]-mx); s+=ex[e]; }
    int i1=0; double b1=ex[0];
    #pragma unroll
    for (int e=1;e<8;e++) if (ex[e]>b1){ b1=ex[e]; i1=e; }
    int i2=-1; double b2=-1.0;
    #pragma unroll
    for (int e=0;e<8;e++) if (e!=i1 && ex[e]>b2){ b2=ex[e]; i2=e; }
    probs2[bt*2+0] = (float)(b1/s);
    probs2[bt*2+1] = (float)(b2/s);
    idx2[bt*2+0] = i1;
    idx2[bt*2+1] = i2;
  }
}

// ---- fused fc+gate transpose: fp32[z][C][H] x2 -> bf16[z][4096][1024] interleaved ----
// dst row n: q=n>>5, r=n&31; r<16 -> fc col q*16+r ; r>=16 -> gate col q*16+(r-16)
__global__ __launch_bounds__(256) void transp_fcg_kernel(
    const float* __restrict__ fc, const float* __restrict__ gate,
    unsigned short* __restrict__ dst)
{
  __shared__ float t[32][33];
  int e = blockIdx.z;
  int n0 = blockIdx.x*32, k0 = blockIdx.y*32;   // n0: source col (H), k0: source row (C)
  int tx = threadIdx.x & 31, ty = threadIdx.x >> 5;
  #pragma unroll
  for (int sel=0; sel<2; ++sel){
    const float* s = (sel ? gate : fc) + ((size_t)e*C_ + k0)*H_ + n0;
    #pragma unroll
    for (int i=0;i<32;i+=8) t[ty+i][tx] = s[(size_t)(ty+i)*H_ + tx];
    __syncthreads();
    #pragma unroll
    for (int i=0;i<32;i+=8){
      int jj = ty+i;                                   // source col within tile
      int drow = n0*2 + ((jj & 16) << 1) + sel*16 + (jj & 15);
      dst[((size_t)e*4096 + drow)*1024 + k0 + tx] = f2bf(t[tx][jj]);
    }
    __syncthreads();
  }
}

// ---------------- weight transpose fp32[z][K][N] -> bf16[z][N][K] (for w_c_proj) ----------------
__global__ __launch_bounds__(256) void transp_kernel(
    const float* __restrict__ src, unsigned short* __restrict__ dst, int K, int N)
{
  __shared__ float t[32][33];
  int e = blockIdx.z;
  int n0 = blockIdx.x*32, k0 = blockIdx.y*32;
  int tx = threadIdx.x & 31, ty = threadIdx.x >> 5;
  const float* s = src + ((size_t)e*K + k0)*N + n0;
  #pragma unroll
  for (int i=0;i<32;i+=8) t[ty+i][tx] = s[(size_t)(ty+i)*N + tx];
  __syncthreads();
  unsigned short* d = dst + ((size_t)e*N + n0)*K + k0;
  #pragma unroll
  for (int i=0;i<32;i+=8) d[(size_t)(ty+i)*K + tx] = f2bf(t[tx][ty+i]);
}

// ---------------- dispatch scan: exact k-major cumsum slot assignment ----------------
__global__ void scan_kernel(const int* __restrict__ idx2, int* __restrict__ pos, int* __restrict__ cnt)
{
  int b = blockIdx.x, lane = threadIdx.x;  // 64 threads
  unsigned long long below = (lane == 0) ? 0ull : (~0ull >> (64 - lane));
  int base = 0;  // lanes 0..7 hold per-expert running counts
  for (int k=0;k<2;k++){
    for (int c0=0;c0<T_;c0+=64){
      int t = c0 + lane;
      int e = idx2[((b*T_ + t)<<1) + k];
      unsigned long long mym = 0; int addv = 0;
      #pragma unroll
      for (int ee=0; ee<8; ++ee){
        unsigned long long m = __ballot(e == ee);
        if (ee == e) mym = m;
        if (lane == ee) addv = __popcll(m);
      }
      int mybase = __shfl(base, e, 64);
      pos[((b*T_+t)<<1)+k] = mybase + __popcll(mym & below);
      base += addv;
    }
  }
  if (lane < 8) cnt[b*8 + lane] = (base < CAP_) ? base : CAP_;
}

__global__ void offsets_kernel(const int* __restrict__ cnt, int* __restrict__ off, int* __restrict__ Me)
{
  int e = threadIdx.x;
  if (e < 8){
    int s = 0;
    for (int b=0;b<8;b++){ off[e*8+b] = s; s += cnt[b*8+e]; }
    Me[e] = s;
  }
}

__global__ void fill_kernel(const int* __restrict__ idx2, const int* __restrict__ pos,
                            const int* __restrict__ off, const float* __restrict__ probs2,
                            int* __restrict__ token_src, float* __restrict__ row_prob)
{
  int a = blockIdx.x*256 + threadIdx.x;
  if (a >= BT_*2) return;
  int bt = a >> 1, k = a & 1;
  int b = bt >> 11;
  int e = idx2[bt*2+k];
  int p = pos[bt*2+k];
  if (p < CAP_){
    int r = e*RPE_ + off[e*8+b] + p;
    token_src[r] = bt;
    row_prob[r] = probs2[bt*2+k];
  }
}

// ---------------- GEMM1: [h|g] = Xg @ Wifcg^T (interleaved), epilogue silu(g)*h ----------------
__global__ __launch_bounds__(256) void gemm1_kernel(
    const unsigned short* __restrict__ xbf,
    const unsigned short* __restrict__ wifcg,  // per-chunk base: [NE][4096][1024]
    const int* __restrict__ token_src,         // global [E][RPE]
    const int* __restrict__ Me,
    unsigned short* __restrict__ act,          // chunk-local [NE][RPE][H]
    int e0)
{
  const int ez = blockIdx.z, e = e0 + ez, mt = blockIdx.y, nt = blockIdx.x; // nt 0..31
  const int M = Me[e];
  if (mt*128 >= M) return;

  __shared__ __align__(16) unsigned char lds[2][32768];   // [buf][A 16K | B 16K]

  const int tid = threadIdx.x;
  const int w = tid >> 6, l = tid & 63;
  const int wrow = w >> 1, wcol = w & 1;
  const int r8 = l >> 3;
  const unsigned swz16 = (unsigned)(((l & 7) ^ r8) * 16);

  unsigned offA[4], offB[4], ldsOff[4];
  #pragma unroll
  for (int j = 0; j < 4; ++j){
    int row = w*32 + j*8 + r8;
    int tok = token_src[e*RPE_ + mt*128 + row];
    offA[j]  = (unsigned)tok * 2048u + swz16;
    offB[j]  = (unsigned)(ez*4096 + nt*128 + row) * 2048u + swz16;
    ldsOff[j] = (unsigned)(w*32 + j*8) * 128u;
  }

  f32x4 acc[4][4];
  #pragma unroll
  for (int i=0;i<4;i++)
    #pragma unroll
    for (int j=0;j<4;j++) acc[i][j] = (f32x4){0.f,0.f,0.f,0.f};

  const unsigned char* gA = (const unsigned char*)xbf;
  const unsigned char* gB = (const unsigned char*)wifcg;

  auto stage = [&](int kt, int bb){
    const unsigned kb = (unsigned)kt * 128u;   // 64 bf16 = 128B per K-tile
    #pragma unroll
    for (int j=0;j<4;++j) GLD16(gA + offA[j] + kb, &lds[bb][0]     + ldsOff[j]);
    #pragma unroll
    for (int j=0;j<4;++j) GLD16(gB + offB[j] + kb, &lds[bb][16384] + ldsOff[j]);
  };
  auto compute = [&](int bb){
    #pragma unroll
    for (int kh=0; kh<2; ++kh){
      bf16x8 afr[4], bfr[4];
      #pragma unroll
      for (int fm=0; fm<4; ++fm){
        int row = wrow*64 + fm*16 + (l & 15);
        int gnum = kh*4 + (l >> 4);
        int byt = row*128 + ((gnum ^ (row & 7)) * 16);
        afr[fm] = *(const bf16x8*)(&lds[bb][0] + byt);
      }
      #pragma unroll
      for (int fn=0; fn<4; ++fn){
        int row = wcol*64 + fn*16 + (l & 15);
        int gnum = kh*4 + (l >> 4);
        int byt = row*128 + ((gnum ^ (row & 7)) * 16);
        bfr[fn] = *(const bf16x8*)(&lds[bb][16384] + byt);
      }
      #pragma unroll
      for (int fm=0; fm<4; ++fm)
        #pragma unroll
        for (int fn=0; fn<4; ++fn)
          acc[fm][fn] = __builtin_amdgcn_mfma_f32_16x16x32_bf16(afr[fm], bfr[fn], acc[fm][fn], 0,0,0);
    }
  };

  stage(0, 0);
  __syncthreads();
  for (int kt = 0; kt < 16; ++kt){
    if (kt+1 < 16) stage(kt+1, (kt+1)&1);
    compute(kt&1);
    __syncthreads();
  }

  // epilogue: fragment pairs (2t = h, 2t+1 = g) share logical cols; act = silu(g)*h
  #pragma unroll
  for (int fm=0; fm<4; ++fm){
    #pragma unroll
    for (int t=0; t<2; ++t){
      f32x4 h = acc[fm][2*t], g = acc[fm][2*t+1];
      #pragma unroll
      for (int r=0; r<4; ++r){
        int row = mt*128 + wrow*64 + fm*16 + (l>>4)*4 + r;
        int col = nt*64 + wcol*32 + t*16 + (l & 15);
        float gv = g[r];
        float a = (gv / (1.f + __expf(-gv))) * h[r];
        act[((size_t)ez*RPE_ + row)*(size_t)H_ + col] = f2bf(a);
      }
    }
  }
}

// ---------------- GEMM2: o = act @ WprojT^T, scatter p*o into y (atomic) ----------------
__global__ __launch_bounds__(256) void gemm2_kernel(
    const unsigned short* __restrict__ act,     // chunk-local [NE][RPE][H]
    const unsigned short* __restrict__ wprojT,  // per-chunk base: [NE][C][H]
    const int* __restrict__ token_src,
    const float* __restrict__ row_prob,
    const int* __restrict__ Me,
    float* __restrict__ y,
    int e0)
{
  const int ez = blockIdx.z, e = e0 + ez, mt = blockIdx.y, nt = blockIdx.x;  // nt 0..7
  const int M = Me[e];
  if (mt*128 >= M) return;

  __shared__ __align__(16) unsigned char lds[2][32768];

  const int tid = threadIdx.x;
  const int w = tid >> 6, l = tid & 63;
  const int wrow = w >> 1, wcol = w & 1;
  const int r8 = l >> 3;
  const unsigned swz16 = (unsigned)(((l & 7) ^ r8) * 16);

  unsigned offA[4], offB[4], ldsOff[4];
  #pragma unroll
  for (int j = 0; j < 4; ++j){
    int row = w*32 + j*8 + r8;
    offA[j] = (unsigned)(ez*RPE_ + mt*128 + row) * 4096u + swz16;
    offB[j] = (unsigned)(ez*C_ + nt*128 + row) * 4096u + swz16;
    ldsOff[j] = (unsigned)(w*32 + j*8) * 128u;
  }

  f32x4 acc[4][4];
  #pragma unroll
  for (int i=0;i<4;i++)
    #pragma unroll
    for (int j=0;j<4;j++) acc[i][j] = (f32x4){0.f,0.f,0.f,0.f};

  const unsigned char* gA = (const unsigned char*)act;
  const unsigned char* gB = (const unsigned char*)wprojT;

  auto stage = [&](int kt, int bb){
    const unsigned kb = (unsigned)kt * 128u;
    #pragma unroll
    for (int j=0;j<4;++j) GLD16(gA + offA[j] + kb, &lds[bb][0]     + ldsOff[j]);
    #pragma unroll
    for (int j=0;j<4;++j) GLD16(gB + offB[j] + kb, &lds[bb][16384] + ldsOff[j]);
  };
  auto compute = [&](int bb){
    #pragma unroll
    for (int kh=0; kh<2; ++kh){
      bf16x8 afr[4], bfr[4];
      #pragma unroll
      for (int fm=0; fm<4; ++fm){
        int row = wrow*64 + fm*16 + (l & 15);
        int gnum = kh*4 + (l >> 4);
        int byt = row*128 + ((gnum ^ (row & 7)) * 16);
        afr[fm] = *(const bf16x8*)(&lds[bb][0] + byt);
      }
      #pragma unroll
      for (int fn=0; fn<4; ++fn){
        int row = wcol*64 + fn*16 + (l & 15);
        int gnum = kh*4 + (l >> 4);
        int byt = row*128 + ((gnum ^ (row & 7)) * 16);
        bfr[fn] = *(const bf16x8*)(&lds[bb][16384] + byt);
      }
      #pragma unroll
      for (int fm=0; fm<4; ++fm)
        #pragma unroll
        for (int fn=0; fn<4; ++fn)
          acc[fm][fn] = __builtin_amdgcn_mfma_f32_16x16x32_bf16(afr[fm], bfr[fn], acc[fm][fn], 0,0,0);
    }
  };

  stage(0, 0);
  __syncthreads();
  for (int kt = 0; kt < 32; ++kt){
    if (kt+1 < 32) stage(kt+1, (kt+1)&1);
    compute(kt&1);
    __syncthreads();
  }

  #pragma unroll
  for (int fm=0; fm<4; ++fm){
    #pragma unroll
    for (int r=0; r<4; ++r){
      int rloc = mt*128 + wrow*64 + fm*16 + (l>>4)*4 + r;
      if (rloc < M){
        int bt  = token_src[e*RPE_ + rloc];
        float p = row_prob[e*RPE_ + rloc];
        float* yrow = y + (size_t)bt*C_;
        #pragma unroll
        for (int fn=0; fn<4; ++fn){
          int col = nt*128 + wcol*64 + fn*16 + (l & 15);
          atomicAdd(yrow + col, p * acc[fm][fn][r]);
        }
      }
    }
  }
}

extern "C" void kernel_launch(void* const* d_in, const int* in_sizes, int n_in,
                              void* d_out, int out_size, void* d_ws, size_t ws_size,
                              hipStream_t stream)
{
  const float* x   = (const float*)d_in[0];
  const float* wr  = (const float*)d_in[1];
  const float* wfc = (const float*)d_in[2];
  const float* wg  = (const float*)d_in[3];
  const float* wpj = (const float*)d_in[4];
  float* y = (float*)d_out;

  unsigned char* ws = (unsigned char*)d_ws;
  const size_t szXBF  = (size_t)BT_*C_*2;            // 33,554,432
  const size_t szFCGc = (size_t)NE_*4096*1024*2;     // 16,777,216
  const size_t szWPc  = (size_t)NE_*C_*H_*2;         //  8,388,608
  const size_t szFCGa = (size_t)E_*4096*1024*2;      // 67,108,864
  const size_t szWPa  = (size_t)E_*C_*H_*2;          // 33,554,432
  const size_t szACT  = (size_t)NE_*RPE_*H_*2;       // 41,943,040
  const size_t szMISC = 3*131072 + 2*(size_t)E_*RPE_*4 + 1024;

  const size_t need_small = szXBF + szFCGc + szWPc + szACT + szMISC;
  const size_t need_big   = szXBF + szFCGa + szWPa + szACT + szMISC;
  if (ws_size < need_small) return;
  const bool big = (ws_size >= need_big);

  const size_t szFCG = big ? szFCGa : szFCGc;
  const size_t szWP  = big ? szWPa  : szWPc;

  size_t oXBF = 0;
  size_t oFCG = oXBF + szXBF;
  size_t oWP  = oFCG + szFCG;
  size_t oACT = oWP  + szWP;
  size_t oM   = oACT + szACT;

  unsigned short* xbf    = (unsigned short*)(ws + oXBF);
  unsigned short* wifcg  = (unsigned short*)(ws + oFCG);
  unsigned short* wprojT = (unsigned short*)(ws + oWP);
  unsigned short* actc   = (unsigned short*)(ws + oACT);

  float* probs2    = (float*)(ws + oM);
  int*   idx2      = (int*)(ws + oM + 1*131072);
  int*   pos       = (int*)(ws + oM + 2*131072);
  int*   token_src = (int*)(ws + oM + 3*131072);
  float* row_prob  = (float*)(ws + oM + 3*131072 + (size_t)E_*RPE_*4);
  int*   cnt       = (int*)(ws + oM + 3*131072 + 2*(size_t)E_*RPE_*4);
  int*   off       = cnt + 64;
  int*   Me        = off + 64;

  hipMemsetAsync(y, 0, (size_t)out_size*4, stream);
  hipMemsetAsync(token_src, 0, (size_t)E_*RPE_*4, stream);

  router_kernel<<<BT_, 256, 0, stream>>>(x, wr, xbf, probs2, idx2);
  scan_kernel<<<B_, 64, 0, stream>>>(idx2, pos, cnt);
  offsets_kernel<<<1, 64, 0, stream>>>(cnt, off, Me);
  fill_kernel<<<(BT_*2+255)/256, 256, 0, stream>>>(idx2, pos, off, probs2, token_src, row_prob);

  if (big){
    transp_fcg_kernel<<<dim3(H_/32, C_/32, E_), 256, 0, stream>>>(wfc, wg, wifcg);
    transp_kernel<<<dim3(C_/32, H_/32, E_), 256, 0, stream>>>(wpj, wprojT, H_, C_);
  }

  for (int e0 = 0; e0 < E_; e0 += NE_){
    unsigned short* wfcg_c = wifcg;
    unsigned short* wpj_c  = wprojT;
    if (big){
      wfcg_c = wifcg  + (size_t)e0*4096*1024;
      wpj_c  = wprojT + (size_t)e0*C_*H_;
    } else {
      transp_fcg_kernel<<<dim3(H_/32, C_/32, NE_), 256, 0, stream>>>(
          wfc + (size_t)e0*C_*H_, wg + (size_t)e0*C_*H_, wifcg);
      transp_kernel<<<dim3(C_/32, H_/32, NE_), 256, 0, stream>>>(
          wpj + (size_t)e0*H_*C_, wprojT, H_, C_);
    }
    gemm1_kernel<<<dim3(4096/128, RPE_/128, NE_), 256, 0, stream>>>(
        xbf, wfcg_c, token_src, Me, actc, e0);
    gemm2_kernel<<<dim3(C_/128, RPE_/128, NE_), 256, 0, stream>>>(
        actc, wpj_c, token_src, row_prob, Me, y, e0);
  }
}